// Round 2
// baseline (454.399 us; speedup 1.0000x reference)
//
#include <hip/hip_runtime.h>

// Problem constants (fixed by the reference)
#define CCH   640      // channels
#define RDIM  128      // MLP hidden
#define HWPIX 100      // H*W
#define NBS   25       // support batch
#define NBQ   75       // query batch
#define CKK   5760     // C*K*K
#define SF_B  64000    // C*H*W per batch elem

// ---------------- Workspace layout (float offsets) ----------------
#define OFF_P0   0
#define OFF_PA   16000
#define OFF_PB   32000
#define OFF_ATA  48000
#define OFF_ATB  53760
#define OFF_BA   59520
#define OFF_BB   59536
#define OFF_H    59552
#define OFF_CKT  65952
#define OFF_CKS  209952
#define OFF_SKT  353952
#define OFF_SKS  376452
#define OFF_TASK 398952

// pooled(sf) -> transposed [c][b]
__global__ void pool_kernel(const float* __restrict__ sf, float* __restrict__ outT) {
    int idx = blockIdx.x * 256 + threadIdx.x;
    if (idx >= CCH * NBS) return;
    int c = idx / NBS, b = idx % NBS;
    const float4* s4 = (const float4*)(sf + b * SF_B + c * HWPIX);
    float acc = 0.f;
#pragma unroll
    for (int q = 0; q < 25; ++q) {
        float4 v = s4[q];
        acc += (v.x + v.y) + (v.z + v.w);
    }
    outT[idx] = acc * 0.01f;
}

// One chain stage: pooled' = Wp*pooled + bp ; A' = A*Wa ; beta' = beta + A*ba
// A stored transposed [c][k]; `first` reads A from Ws ([k][c]) and beta from bs.
__global__ void chain_step(const float* __restrict__ inP, const float* __restrict__ Wp,
                           const float* __restrict__ bp, float* __restrict__ outP,
                           const float* __restrict__ inA, const float* __restrict__ Wa,
                           const float* __restrict__ ba, const float* __restrict__ inB,
                           float* __restrict__ outA, float* __restrict__ outB,
                           int first, const float* __restrict__ Ws, const float* __restrict__ bs) {
    int blk = blockIdx.x, t = threadIdx.x;
    if (blk < 63) {
        int idx = blk * 256 + t;
        if (idx >= CCH * NBS) return;
        int o = idx / NBS, b = idx % NBS;
        const float4* w4 = (const float4*)(Wp + o * CCH);
        float acc = bp[o];
        for (int c4 = 0; c4 < CCH / 4; ++c4) {
            float4 w = w4[c4];
            int c = c4 * 4;
            acc += w.x * inP[c * NBS + b] + w.y * inP[(c + 1) * NBS + b]
                 + w.z * inP[(c + 2) * NBS + b] + w.w * inP[(c + 3) * NBS + b];
        }
        outP[idx] = acc;
    } else if (blk < 86) {
        int idx = (blk - 63) * 256 + t;
        if (idx >= CCH * 9) return;
        int c = idx / 9, k = idx % 9;
        float acc = 0.f;
        if (first) {
            for (int o = 0; o < CCH; ++o) acc += Ws[k * CCH + o] * Wa[o * CCH + c];
        } else {
            for (int o = 0; o < CCH; ++o) acc += inA[o * 9 + k] * Wa[o * CCH + c];
        }
        outA[idx] = acc;   // [c][k]
    } else {
        if (t < 9) {
            float acc = first ? bs[t] : inB[t];
            if (first) {
                for (int o = 0; o < CCH; ++o) acc += Ws[t * CCH + o] * ba[o];
            } else {
                for (int o = 0; o < CCH; ++o) acc += inA[o * 9 + t] * ba[o];
            }
            outB[t] = acc;
        }
    }
}

// h = relu(pooled @ W1 + b1) for both branches; pair = branch*25 + b
__global__ void mlp_phase1(const float* __restrict__ Pt, const float* __restrict__ Ps,
                           const float* __restrict__ W1, const float* __restrict__ b1,
                           float* __restrict__ Hbuf) {
    int idx = blockIdx.x * 256 + threadIdx.x;
    if (idx >= 50 * RDIM) return;
    int pair = idx >> 7, r = idx & 127;
    int branch = pair / NBS, b = pair % NBS;
    const float* P = branch ? Ps : Pt;
    float acc = b1[r];
    for (int c = 0; c < CCH; ++c) acc += P[c * NBS + b] * W1[c * RDIM + r];
    Hbuf[idx] = fmaxf(acc, 0.f);
}

// ck = h @ W2 + b2 ; grid = 50 pairs x 10 j-chunks of 576
__global__ void mlp_phase2(const float* __restrict__ Hbuf, const float* __restrict__ W2,
                           const float* __restrict__ b2, float* __restrict__ ckt,
                           float* __restrict__ cks) {
    __shared__ float hs[RDIM];
    int pair = blockIdx.x / 10, jc = blockIdx.x % 10;
    int t = threadIdx.x;
    int branch = pair / NBS, b = pair % NBS;
    if (t < RDIM) hs[t] = Hbuf[pair * RDIM + t];
    __syncthreads();
    float* ck = (branch ? cks : ckt) + b * CKK;
    int j0 = jc * 576;
    for (int j = j0 + t; j < j0 + 576; j += 256) {
        float acc = b2[j];
#pragma unroll 4
        for (int r = 0; r < RDIM; ++r) acc += hs[r] * W2[r * CKK + j];
        ck[j] = acc;
    }
}

// sk for both branches: branch0 uses composed A4/beta on sf, branch1 raw Ws/bs on sf.
// Output stored in RAW layout [b][k*100 + q] (k = conv channel 0..8, q = pixel).
// Consumers index the flat view: sk_view[b,p,uv] = raw[b*900 + 9p+uv].
__global__ void sk_kernel(const float* __restrict__ sf, const float* __restrict__ A4T,
                          const float* __restrict__ betaF, const float* __restrict__ Ws,
                          const float* __restrict__ bs, float* __restrict__ skt,
                          float* __restrict__ sks) {
    int idx = blockIdx.x * 256 + threadIdx.x;
    if (idx >= 2 * NBS * 9 * HWPIX) return;
    int branch = idx / (NBS * 900);
    int r = idx % (NBS * 900);
    int b = r / 900;
    int r2 = r % 900;            // raw flat index = k*100 + q
    int k = r2 / HWPIX, q = r2 % HWPIX;
    const float* x = sf + b * SF_B + q;
    float acc;
    if (branch == 0) {
        acc = betaF[k];
        for (int c = 0; c < CCH; ++c) acc += A4T[c * 9 + k] * x[c * HWPIX];
    } else {
        acc = bs[k];
        const float* wr = Ws + k * CCH;
        for (int c = 0; c < CCH; ++c) acc += wr[c] * x[c * HWPIX];
    }
    (branch ? sks : skt)[b * 900 + r2] = acc;   // RAW layout store (coalesced)
}

// task[c][p*9+uv] = (1/25) sum_b ckt[b][c*9+uv] * skt_raw[b][9p+uv]
__global__ void task_assemble(const float* __restrict__ ckt, const float* __restrict__ skt,
                              float* __restrict__ task) {
    int idx = blockIdx.x * 256 + threadIdx.x;
    if (idx >= CCH * 900) return;
    int c = idx / 900;
    int r = idx % 900;       // p*9+uv, also the raw-flat view offset
    int uv = idx % 9;
    float acc = 0.f;
#pragma unroll
    for (int b = 0; b < NBS; ++b)
        acc += ckt[b * CKK + c * 9 + uv] * skt[b * 900 + r];
    task[idx] = acc * 0.04f;
}

// adapted_query[b,c,p] = sum_uv task[c,p,uv] * qf_pad[b,c,neigh]
__global__ void inv_query(const float* __restrict__ qf, const float* __restrict__ task,
                          float* __restrict__ out) {
    int idx = blockIdx.x * 256 + threadIdx.x;
    if (idx >= NBQ * SF_B) return;
    int b = idx / SF_B;
    int cp = idx % SF_B;
    int c = cp / HWPIX, p = cp % HWPIX;
    int i = p / 10, j = p % 10;
    const float* tk = task + c * 900 + p * 9;
    const float* x = qf + b * SF_B + c * HWPIX;
    float acc = 0.f;
#pragma unroll
    for (int u = 0; u < 3; ++u) {
        int ii = i + u - 1;
        if (ii < 0 || ii > 9) continue;
#pragma unroll
        for (int v = 0; v < 3; ++v) {
            int jj = j + v - 1;
            if (jj < 0 || jj > 9) continue;
            acc += tk[u * 3 + v] * x[ii * 10 + jj];
        }
    }
    out[idx] = acc;
}

// adapted_support[b,c,p] = sum_uv ck_s[b,c,uv]*sk_s_view[b,p,uv]*task[c,p,uv] * sf_pad[b,c,neigh]
__global__ void inv_support(const float* __restrict__ sf, const float* __restrict__ task,
                            const float* __restrict__ cks, const float* __restrict__ sks,
                            float* __restrict__ out) {
    int idx = blockIdx.x * 256 + threadIdx.x;
    if (idx >= NBS * SF_B) return;
    int b = idx / SF_B;
    int cp = idx % SF_B;
    int c = cp / HWPIX, p = cp % HWPIX;
    int i = p / 10, j = p % 10;
    const float* tk = task + c * 900 + p * 9;
    const float* sv = sks + b * 900 + p * 9;   // raw layout: offset 9p+uv is the view elem
    const float* cv = cks + b * CKK + c * 9;
    const float* x = sf + b * SF_B + c * HWPIX;
    float acc = 0.f;
#pragma unroll
    for (int u = 0; u < 3; ++u) {
        int ii = i + u - 1;
        if (ii < 0 || ii > 9) continue;
#pragma unroll
        for (int v = 0; v < 3; ++v) {
            int jj = j + v - 1;
            if (jj < 0 || jj > 9) continue;
            int uv = u * 3 + v;
            acc += cv[uv] * sv[uv] * tk[uv] * x[ii * 10 + jj];
        }
    }
    out[idx] = acc;
}

extern "C" void kernel_launch(void* const* d_in, const int* in_sizes, int n_in,
                              void* d_out, int out_size, void* d_ws, size_t ws_size,
                              hipStream_t stream) {
    const float* sf  = (const float*)d_in[0];
    const float* qf  = (const float*)d_in[1];
    const float* Wc[4] = {(const float*)d_in[2], (const float*)d_in[4],
                          (const float*)d_in[6], (const float*)d_in[8]};
    const float* bc[4] = {(const float*)d_in[3], (const float*)d_in[5],
                          (const float*)d_in[7], (const float*)d_in[9]};
    const float* W1 = (const float*)d_in[10];
    const float* b1 = (const float*)d_in[11];
    const float* W2 = (const float*)d_in[12];
    const float* b2 = (const float*)d_in[13];
    const float* Ws = (const float*)d_in[14];
    const float* bs = (const float*)d_in[15];
    float* out = (float*)d_out;
    float* ws = (float*)d_ws;

    float* P0  = ws + OFF_P0;
    float* Pa  = ws + OFF_PA;
    float* Pb  = ws + OFF_PB;
    float* ATa = ws + OFF_ATA;
    float* ATb = ws + OFF_ATB;
    float* Ba  = ws + OFF_BA;
    float* Bb  = ws + OFF_BB;
    float* Hb  = ws + OFF_H;
    float* CKT = ws + OFF_CKT;
    float* CKS = ws + OFF_CKS;
    float* SKT = ws + OFF_SKT;
    float* SKS = ws + OFF_SKS;
    float* TSK = ws + OFF_TASK;

    // 1. pooled support (transposed [c][b])
    pool_kernel<<<63, 256, 0, stream>>>(sf, P0);

    // 2. chain: pooled through Wc1..Wc4 ; A = Ws*Wc4*Wc3*Wc2*Wc1 ; beta folded
    chain_step<<<87, 256, 0, stream>>>(P0, Wc[0], bc[0], Pa, nullptr, Wc[3], bc[3], nullptr,
                                       ATa, Ba, 1, Ws, bs);
    chain_step<<<87, 256, 0, stream>>>(Pa, Wc[1], bc[1], Pb, ATa, Wc[2], bc[2], Ba,
                                       ATb, Bb, 0, Ws, bs);
    chain_step<<<87, 256, 0, stream>>>(Pb, Wc[2], bc[2], Pa, ATb, Wc[1], bc[1], Bb,
                                       ATa, Ba, 0, Ws, bs);
    chain_step<<<87, 256, 0, stream>>>(Pa, Wc[3], bc[3], Pb, ATa, Wc[0], bc[0], Ba,
                                       ATb, Bb, 0, Ws, bs);
    // final: pooled_t = Pb, A4^T = ATb, beta4 = Bb

    // 3. MLP (both branches)
    mlp_phase1<<<25, 256, 0, stream>>>(Pb, P0, W1, b1, Hb);
    mlp_phase2<<<500, 256, 0, stream>>>(Hb, W2, b2, CKT, CKS);

    // 4. spatial kernels (both branches)
    sk_kernel<<<(2 * NBS * 900 + 255) / 256, 256, 0, stream>>>(sf, ATb, Bb, Ws, bs, SKT, SKS);

    // 5. task kernel assembly
    task_assemble<<<(CCH * 900 + 255) / 256, 256, 0, stream>>>(CKT, SKT, TSK);

    // 6. involutions
    inv_support<<<(NBS * SF_B + 255) / 256, 256, 0, stream>>>(sf, TSK, CKS, SKS, out);
    inv_query<<<(NBQ * SF_B + 255) / 256, 256, 0, stream>>>(qf, TSK, out + NBS * SF_B);
}

// Round 3
// 302.674 us; speedup vs baseline: 1.5013x; 1.5013x over previous
//
#include <hip/hip_runtime.h>

#define CCH   640
#define RDIM  128
#define HWPIX 100
#define NBS   25
#define NBQ   75
#define CKK   5760
#define SF_B  64000

// ---------------- Workspace layout (float offsets) ----------------
#define OFF_PG0  0        // [25][640] pooled, b-major
#define OFF_PGA  16000    // chain ping
#define OFF_PGB  32000    // chain pong
#define OFF_ATA  48000    // [640][9]
#define OFF_ATB  53760
#define OFF_BA   59520    // [16]
#define OFF_BB   59536
#define OFF_HP   59552    // [50][4][128] mlp1 partials
#define OFF_SKT  85152    // [2][25][900] raw layout parts
#define OFF_SKS  130152   // [2][25][900]
#define OFF_SKSC 175152   // [25][900] combined
#define OFF_CKT  197652   // [25][5760]
#define OFF_CKS  341652   // [25][5760]
#define OFF_TASK 485652   // [640][900]

// pooled(sf) -> [b][c] layout
__global__ void pool_kernel(const float* __restrict__ sf, float* __restrict__ Pg0) {
    int idx = blockIdx.x * 256 + threadIdx.x;
    if (idx >= NBS * CCH) return;
    int b = idx / CCH, c = idx % CCH;
    const float4* s4 = (const float4*)(sf + b * SF_B + c * HWPIX);
    float acc = 0.f;
#pragma unroll
    for (int q = 0; q < 25; ++q) {
        float4 v = s4[q];
        acc += (v.x + v.y) + (v.z + v.w);
    }
    Pg0[idx] = acc * 0.01f;
}

// One chain stage, wave-parallel.
// Blocks [0,4000): P' = Wp*P + bp  (wave per output (o,b))
// Blocks [4000,4023): A' = A*Wa  (wave per (k, 64-c group), serial o loop)
// Blocks [4023,4026): beta' = beta + A*ba (wave per k)
__global__ void chain_step(const float* __restrict__ Pin, const float* __restrict__ Wp,
                           const float* __restrict__ bp, float* __restrict__ Pout,
                           const float* __restrict__ Ain, const float* __restrict__ Wa,
                           const float* __restrict__ ba, const float* __restrict__ Bin,
                           float* __restrict__ Aout, float* __restrict__ Bout,
                           int first, const float* __restrict__ Ws, const float* __restrict__ bs) {
    int blk = blockIdx.x, t = threadIdx.x;
    int lane = t & 63;
    if (blk < 4000) {
        int W = blk * 4 + (t >> 6);          // 0..15999
        int o = W / NBS, b = W % NBS;
        const float* wrow = Wp + o * CCH;
        const float* prow = Pin + b * CCH;
        float acc = 0.f;
#pragma unroll
        for (int s = 0; s < 10; ++s) {
            int c = s * 64 + lane;
            acc += wrow[c] * prow[c];
        }
#pragma unroll
        for (int m = 32; m >= 1; m >>= 1) acc += __shfl_xor(acc, m);
        if (lane == 0) Pout[b * CCH + o] = acc + bp[o];
    } else if (blk < 4023) {
        int WA = (blk - 4000) * 4 + (t >> 6);
        if (WA >= 90) return;
        int k = WA / 10, cg = WA % 10;
        int c = cg * 64 + lane;
        float acc = 0.f;
        if (first) {
            const float* arow = Ws + k * CCH;
            for (int o = 0; o < CCH; ++o) acc += arow[o] * Wa[o * CCH + c];
        } else {
            for (int o = 0; o < CCH; ++o) acc += Ain[o * 9 + k] * Wa[o * CCH + c];
        }
        Aout[c * 9 + k] = acc;
    } else {
        int WB = (blk - 4023) * 4 + (t >> 6);
        if (WB >= 9) return;
        int k = WB;
        float acc = 0.f;
        if (first) {
            const float* arow = Ws + k * CCH;
#pragma unroll
            for (int s = 0; s < 10; ++s) {
                int o = s * 64 + lane;
                acc += arow[o] * ba[o];
            }
        } else {
#pragma unroll
            for (int s = 0; s < 10; ++s) {
                int o = s * 64 + lane;
                acc += Ain[o * 9 + k] * ba[o];
            }
        }
#pragma unroll
        for (int m = 32; m >= 1; m >>= 1) acc += __shfl_xor(acc, m);
        if (lane == 0) Bout[k] = acc + (first ? bs[k] : Bin[k]);
    }
}

// mlp1 K-split partials + fused sk (both branches, c-split x2)
// Blocks [0,100): mlp1 partial: pair=blk/2, slice=(blk%2)*2+(t/128)
// Blocks [100,276): sk
__global__ void postchain(const float* __restrict__ sf, const float* __restrict__ Pg0,
                          const float* __restrict__ Pgf, const float* __restrict__ W1,
                          float* __restrict__ Hp, const float* __restrict__ A4T,
                          const float* __restrict__ betaF, const float* __restrict__ Ws,
                          const float* __restrict__ bs, float* __restrict__ SKT,
                          float* __restrict__ SKS) {
    int blk = blockIdx.x, t = threadIdx.x;
    if (blk < 100) {
        int pair = blk / 2;
        int s = (blk % 2) * 2 + (t >> 7);
        int r = t & 127;
        int branch = pair / NBS, b = pair % NBS;
        const float* prow = (branch ? Pg0 : Pgf) + b * CCH;
        int c0 = s * 160;
        float acc = 0.f;
        for (int c = 0; c < 160; ++c)
            acc += prow[c0 + c] * W1[(c0 + c) * RDIM + r];
        Hp[(pair * 4 + s) * RDIM + r] = acc;
    } else {
        int sidx = (blk - 100) * 256 + t;
        if (sidx >= 45000) return;
        int s = sidx / 22500;
        int rem = sidx % 22500;
        int b = rem / 900;
        int r2 = rem % 900;          // raw flat: k*100 + q
        int k = r2 / HWPIX, q = r2 % HWPIX;
        const float* x = sf + b * SF_B + q;
        const float* wsr = Ws + k * CCH;
        int c0 = s * 320;
        float acc0 = 0.f, acc1 = 0.f;
        for (int c = 0; c < 320; ++c) {
            float xc = x[(c0 + c) * HWPIX];
            acc0 += A4T[(c0 + c) * 9 + k] * xc;
            acc1 += wsr[c0 + c] * xc;
        }
        if (s == 0) { acc0 += betaF[k]; acc1 += bs[k]; }
        SKT[sidx] = acc0;
        SKS[sidx] = acc1;
    }
}

// ck = relu(bias + sum partials) @ W2 + b2 ; grid (50 pairs x 9 chunks of 640), 320 thr
__global__ void mlp_phase2(const float* __restrict__ Hp, const float* __restrict__ b1,
                           const float* __restrict__ W2, const float* __restrict__ b2,
                           float* __restrict__ ckt, float* __restrict__ cks) {
    __shared__ float hs[RDIM];
    int pair = blockIdx.x / 9, chunk = blockIdx.x % 9;
    int t = threadIdx.x;
    int branch = pair / NBS, b = pair % NBS;
    if (t < RDIM) {
        const float* hp = Hp + pair * 4 * RDIM;
        hs[t] = fmaxf(b1[t] + hp[t] + hp[RDIM + t] + hp[2 * RDIM + t] + hp[3 * RDIM + t], 0.f);
    }
    __syncthreads();
    int jbase = chunk * 640;
    float acc0 = b2[jbase + t], acc1 = b2[jbase + t + 320];
#pragma unroll 4
    for (int r = 0; r < RDIM; ++r) {
        const float* wrow = W2 + r * CKK + jbase;
        float h = hs[r];
        acc0 += h * wrow[t];
        acc1 += h * wrow[t + 320];
    }
    float* ck = (branch ? cks : ckt) + b * CKK + jbase;
    ck[t] = acc0;
    ck[t + 320] = acc1;
}

// task[c][r] = (1/25) sum_b ckt[b][c*9+uv] * (SKT0+SKT1)[b][r]  (blocks < 2250)
// blocks [2250,2338): combine SKS parts -> SKSc
__global__ void task_assemble(const float* __restrict__ ckt, const float* __restrict__ SKT,
                              const float* __restrict__ SKS, float* __restrict__ task,
                              float* __restrict__ SKSc) {
    int blk = blockIdx.x, t = threadIdx.x;
    if (blk < 2250) {
        int idx = blk * 256 + t;
        if (idx >= CCH * 900) return;
        int c = idx / 900;
        int r = idx % 900;
        int uv = idx % 9;
        float acc = 0.f;
#pragma unroll
        for (int b = 0; b < NBS; ++b)
            acc += ckt[b * CKK + c * 9 + uv] * (SKT[b * 900 + r] + SKT[22500 + b * 900 + r]);
        task[idx] = acc * 0.04f;
    } else {
        int cidx = (blk - 2250) * 256 + t;
        if (cidx >= 22500) return;
        SKSc[cidx] = SKS[cidx] + SKS[22500 + cidx];
    }
}

// Merged involutions, one thread per image row (b,c,i).
// Blocks [0,625): support (needs cks, sksc). Blocks [625,2500): query.
__global__ void involutions(const float* __restrict__ sf, const float* __restrict__ qf,
                            const float* __restrict__ task, const float* __restrict__ cks,
                            const float* __restrict__ sksc, float* __restrict__ out) {
    int blk = blockIdx.x, t = threadIdx.x;
    int support = (blk < 625);
    int idx = support ? (blk * 256 + t) : ((blk - 625) * 256 + t);
    int nb = support ? NBS : NBQ;
    if (idx >= nb * CCH * 10) return;
    int c = idx / (nb * 10);
    int rem = idx % (nb * 10);
    int b = rem / 10, i = rem % 10;

    const float* x = (support ? sf : qf) + b * SF_B + c * HWPIX;
    const float* tk = task + c * 900 + i * 90;   // 90 floats for this row

    // padded 3-row window
    float xp[3][12];
#pragma unroll
    for (int u = 0; u < 3; ++u) {
        xp[u][0] = 0.f; xp[u][11] = 0.f;
        int ii = i + u - 1;
        if (ii >= 0 && ii <= 9) {
            const float2* xr = (const float2*)(x + ii * 10);
#pragma unroll
            for (int m = 0; m < 5; ++m) {
                float2 v = xr[m];
                xp[u][1 + 2 * m] = v.x;
                xp[u][2 + 2 * m] = v.y;
            }
        } else {
#pragma unroll
            for (int m = 0; m < 10; ++m) xp[u][1 + m] = 0.f;
        }
    }

    float res[10];
    if (support) {
        const float* cv = cks + b * CKK + c * 9;
        const float* sv = sksc + b * 900 + i * 90;
        float cvr[9];
#pragma unroll
        for (int n = 0; n < 9; ++n) cvr[n] = cv[n];
#pragma unroll
        for (int j = 0; j < 10; ++j) {
            float a = 0.f;
#pragma unroll
            for (int u = 0; u < 3; ++u)
#pragma unroll
                for (int v = 0; v < 3; ++v) {
                    int uv = u * 3 + v;
                    a += cvr[uv] * sv[j * 9 + uv] * tk[j * 9 + uv] * xp[u][j + v];
                }
            res[j] = a;
        }
    } else {
#pragma unroll
        for (int j = 0; j < 10; ++j) {
            float a = 0.f;
#pragma unroll
            for (int u = 0; u < 3; ++u)
#pragma unroll
                for (int v = 0; v < 3; ++v)
                    a += tk[j * 9 + u * 3 + v] * xp[u][j + v];
            res[j] = a;
        }
    }

    float* op = out + (support ? 0 : NBS * SF_B) + b * SF_B + c * HWPIX + i * 10;
    float2* o2 = (float2*)op;
#pragma unroll
    for (int m = 0; m < 5; ++m) {
        float2 v; v.x = res[2 * m]; v.y = res[2 * m + 1];
        o2[m] = v;
    }
}

extern "C" void kernel_launch(void* const* d_in, const int* in_sizes, int n_in,
                              void* d_out, int out_size, void* d_ws, size_t ws_size,
                              hipStream_t stream) {
    const float* sf  = (const float*)d_in[0];
    const float* qf  = (const float*)d_in[1];
    const float* Wc[4] = {(const float*)d_in[2], (const float*)d_in[4],
                          (const float*)d_in[6], (const float*)d_in[8]};
    const float* bc[4] = {(const float*)d_in[3], (const float*)d_in[5],
                          (const float*)d_in[7], (const float*)d_in[9]};
    const float* W1 = (const float*)d_in[10];
    const float* b1 = (const float*)d_in[11];
    const float* W2 = (const float*)d_in[12];
    const float* b2 = (const float*)d_in[13];
    const float* Ws = (const float*)d_in[14];
    const float* bs = (const float*)d_in[15];
    float* out = (float*)d_out;
    float* ws = (float*)d_ws;

    float* Pg0 = ws + OFF_PG0;
    float* Pga = ws + OFF_PGA;
    float* Pgb = ws + OFF_PGB;
    float* ATa = ws + OFF_ATA;
    float* ATb = ws + OFF_ATB;
    float* Ba  = ws + OFF_BA;
    float* Bb  = ws + OFF_BB;
    float* Hp  = ws + OFF_HP;
    float* SKT = ws + OFF_SKT;
    float* SKS = ws + OFF_SKS;
    float* SKSc= ws + OFF_SKSC;
    float* CKT = ws + OFF_CKT;
    float* CKS = ws + OFF_CKS;
    float* TSK = ws + OFF_TASK;

    pool_kernel<<<63, 256, 0, stream>>>(sf, Pg0);

    chain_step<<<4026, 256, 0, stream>>>(Pg0, Wc[0], bc[0], Pga, nullptr, Wc[3], bc[3], nullptr,
                                         ATa, Ba, 1, Ws, bs);
    chain_step<<<4026, 256, 0, stream>>>(Pga, Wc[1], bc[1], Pgb, ATa, Wc[2], bc[2], Ba,
                                         ATb, Bb, 0, Ws, bs);
    chain_step<<<4026, 256, 0, stream>>>(Pgb, Wc[2], bc[2], Pga, ATb, Wc[1], bc[1], Bb,
                                         ATa, Ba, 0, Ws, bs);
    chain_step<<<4026, 256, 0, stream>>>(Pga, Wc[3], bc[3], Pgb, ATa, Wc[0], bc[0], Ba,
                                         ATb, Bb, 0, Ws, bs);
    // pooled_t = Pgb, A4^T = ATb, beta4 = Bb

    postchain<<<276, 256, 0, stream>>>(sf, Pg0, Pgb, W1, Hp, ATb, Bb, Ws, bs, SKT, SKS);
    mlp_phase2<<<450, 320, 0, stream>>>(Hp, b1, W2, b2, CKT, CKS);
    task_assemble<<<2338, 256, 0, stream>>>(CKT, SKT, SKS, TSK, SKSc);
    involutions<<<2500, 256, 0, stream>>>(sf, qf, TSK, CKS, SKSc, out);
}

// Round 4
// 241.640 us; speedup vs baseline: 1.8805x; 1.2526x over previous
//
#include <hip/hip_runtime.h>

#define CCH   640
#define RDIM  128
#define HWPIX 100
#define NBS   25
#define NBQ   75
#define CKK   5760
#define SF_B  64000

// ---------------- Workspace layout (float offsets) ----------------
#define OFF_PG0  0        // [25][640] pooled, b-major
#define OFF_PGA  16000
#define OFF_PGB  32000
#define OFF_ATA  48000    // [640][9]
#define OFF_ATB  53760
#define OFF_BA   59520    // [16]
#define OFF_BB   59536
#define OFF_HP   59552    // [50][4][128] mlp1 partials
#define OFF_SKT  85152    // [2][25][900]
#define OFF_SKS  130152   // [2][25][900]
#define OFF_SKSC 175152   // [25][900]
#define OFF_CKT  197652   // [25][5760]
#define OFF_CKS  341652   // [25][5760]
#define OFF_TASK 485652   // [640][900]

// pooled(sf) -> [b][c] layout; 250 blocks x 64 threads = 16000
__global__ void pool_kernel(const float* __restrict__ sf, float* __restrict__ Pg0) {
    int idx = blockIdx.x * 64 + threadIdx.x;
    if (idx >= NBS * CCH) return;
    int b = idx / CCH, c = idx % CCH;
    const float4* s4 = (const float4*)(sf + b * SF_B + c * HWPIX);
    float acc = 0.f;
#pragma unroll
    for (int q = 0; q < 25; ++q) {
        float4 v = s4[q];
        acc += (v.x + v.y) + (v.z + v.w);
    }
    Pg0[idx] = acc * 0.01f;
}

// One chain stage.
// Blocks [0,4000): P' = Wp*P + bp  (wave per output (o,b), float2 lane loads)
// Blocks [4000,4090): A' = A*Wa   (block per (k, ctile64); 4 o-groups x 160, LDS reduce)
// Blocks [4090,4093): beta' = beta + A*ba (wave per k)
__global__ void chain_step(const float* __restrict__ Pin, const float* __restrict__ Wp,
                           const float* __restrict__ bp, float* __restrict__ Pout,
                           const float* __restrict__ Ain, const float* __restrict__ Wa,
                           const float* __restrict__ ba, const float* __restrict__ Bin,
                           float* __restrict__ Aout, float* __restrict__ Bout,
                           int first, const float* __restrict__ Ws, const float* __restrict__ bs) {
    __shared__ float red[256];
    int blk = blockIdx.x, t = threadIdx.x;
    int lane = t & 63;
    if (blk < 4000) {
        int W = blk * 4 + (t >> 6);          // 0..15999
        int o = W / NBS, b = W % NBS;
        const float2* w2 = (const float2*)(Wp + o * CCH);
        const float2* p2 = (const float2*)(Pin + b * CCH);
        float acc = 0.f;
#pragma unroll
        for (int s = 0; s < 5; ++s) {
            float2 wv = w2[s * 64 + lane];
            float2 pv = p2[s * 64 + lane];
            acc += wv.x * pv.x + wv.y * pv.y;
        }
#pragma unroll
        for (int m = 32; m >= 1; m >>= 1) acc += __shfl_xor(acc, m);
        if (lane == 0) Pout[b * CCH + o] = acc + bp[o];
    } else if (blk < 4090) {
        int w = blk - 4000;                  // 0..89
        int k = w / 10, ctile = w % 10;
        int og = t >> 6, cl = lane;
        int c = ctile * 64 + cl;
        int o0 = og * 160;
        float acc = 0.f;
        if (first) {
            const float* ar = Ws + k * CCH;
#pragma unroll 8
            for (int o = o0; o < o0 + 160; ++o)
                acc += ar[o] * Wa[o * CCH + c];
        } else {
#pragma unroll 8
            for (int o = o0; o < o0 + 160; ++o)
                acc += Ain[o * 9 + k] * Wa[o * CCH + c];
        }
        red[t] = acc;
        __syncthreads();
        if (t < 64) {
            float s = red[t] + red[64 + t] + red[128 + t] + red[192 + t];
            Aout[(ctile * 64 + t) * 9 + k] = s;
        }
    } else {
        int WB = (blk - 4090) * 4 + (t >> 6);
        if (WB >= 9) return;
        int k = WB;
        float acc = 0.f;
        if (first) {
            const float* ar = Ws + k * CCH;
#pragma unroll
            for (int s = 0; s < 10; ++s) acc += ar[s * 64 + lane] * ba[s * 64 + lane];
        } else {
#pragma unroll
            for (int s = 0; s < 10; ++s) acc += Ain[(s * 64 + lane) * 9 + k] * ba[s * 64 + lane];
        }
#pragma unroll
        for (int m = 32; m >= 1; m >>= 1) acc += __shfl_xor(acc, m);
        if (lane == 0) Bout[k] = acc + (first ? bs[k] : Bin[k]);
    }
}

// mlp1 K-split partials + fused sk (both branches, c-split x2)
__global__ void postchain(const float* __restrict__ sf, const float* __restrict__ Pg0,
                          const float* __restrict__ Pgf, const float* __restrict__ W1,
                          float* __restrict__ Hp, const float* __restrict__ A4T,
                          const float* __restrict__ betaF, const float* __restrict__ Ws,
                          const float* __restrict__ bs, float* __restrict__ SKT,
                          float* __restrict__ SKS) {
    int blk = blockIdx.x, t = threadIdx.x;
    if (blk < 100) {
        int pair = blk / 2;
        int s = (blk % 2) * 2 + (t >> 7);
        int r = t & 127;
        int branch = pair / NBS, b = pair % NBS;
        const float* prow = (branch ? Pg0 : Pgf) + b * CCH;
        int c0 = s * 160;
        float acc = 0.f;
#pragma unroll 8
        for (int c = 0; c < 160; ++c)
            acc += prow[c0 + c] * W1[(c0 + c) * RDIM + r];
        Hp[(pair * 4 + s) * RDIM + r] = acc;
    } else {
        int sidx = (blk - 100) * 256 + t;
        if (sidx >= 45000) return;
        int s = sidx / 22500;
        int rem = sidx % 22500;
        int b = rem / 900;
        int r2 = rem % 900;          // raw flat: k*100 + q
        int k = r2 / HWPIX, q = r2 % HWPIX;
        const float* x = sf + b * SF_B + q;
        const float* wsr = Ws + k * CCH;
        int c0 = s * 320;
        float acc0 = 0.f, acc1 = 0.f;
#pragma unroll 8
        for (int c = 0; c < 320; ++c) {
            float xc = x[(c0 + c) * HWPIX];
            acc0 += A4T[(c0 + c) * 9 + k] * xc;
            acc1 += wsr[c0 + c] * xc;
        }
        if (s == 0) { acc0 += betaF[k]; acc1 += bs[k]; }
        SKT[sidx] = acc0;
        SKS[sidx] = acc1;
    }
}

// ck = relu(bias + sum partials) @ W2 + b2
__global__ void mlp_phase2(const float* __restrict__ Hp, const float* __restrict__ b1,
                           const float* __restrict__ W2, const float* __restrict__ b2,
                           float* __restrict__ ckt, float* __restrict__ cks) {
    __shared__ float hs[RDIM];
    int pair = blockIdx.x / 9, chunk = blockIdx.x % 9;
    int t = threadIdx.x;
    int branch = pair / NBS, b = pair % NBS;
    if (t < RDIM) {
        const float* hp = Hp + pair * 4 * RDIM;
        hs[t] = fmaxf(b1[t] + hp[t] + hp[RDIM + t] + hp[2 * RDIM + t] + hp[3 * RDIM + t], 0.f);
    }
    __syncthreads();
    int jbase = chunk * 640;
    float acc0 = b2[jbase + t], acc1 = b2[jbase + t + 320];
#pragma unroll 4
    for (int r = 0; r < RDIM; ++r) {
        const float* wrow = W2 + r * CKK + jbase;
        float h = hs[r];
        acc0 += h * wrow[t];
        acc1 += h * wrow[t + 320];
    }
    float* ck = (branch ? cks : ckt) + b * CKK + jbase;
    ck[t] = acc0;
    ck[t + 320] = acc1;
}

// task + SKS combine
__global__ void task_assemble(const float* __restrict__ ckt, const float* __restrict__ SKT,
                              const float* __restrict__ SKS, float* __restrict__ task,
                              float* __restrict__ SKSc) {
    int blk = blockIdx.x, t = threadIdx.x;
    if (blk < 2250) {
        int idx = blk * 256 + t;
        if (idx >= CCH * 900) return;
        int c = idx / 900;
        int r = idx % 900;
        int uv = idx % 9;
        float acc = 0.f;
#pragma unroll
        for (int b = 0; b < NBS; ++b)
            acc += ckt[b * CKK + c * 9 + uv] * (SKT[b * 900 + r] + SKT[22500 + b * 900 + r]);
        task[idx] = acc * 0.04f;
    } else {
        int cidx = (blk - 2250) * 256 + t;
        if (cidx >= 22500) return;
        SKSc[cidx] = SKS[cidx] + SKS[22500 + cidx];
    }
}

// Merged involutions with LDS-staged per-channel data.
// Blocks [0,2000): support: b = blk/80, cgroup of 8 channels = blk%80.
// Blocks [2000,3920): query: c = (blk-2000)/3, bgroup of 25 = (blk-2000)%3.
__global__ __launch_bounds__(256, 4) void involutions(
        const float* __restrict__ sf, const float* __restrict__ qf,
        const float* __restrict__ task, const float* __restrict__ cks,
        const float* __restrict__ sksc, float* __restrict__ out) {
    __shared__ float lds[8 * 900 + 900 + 72];   // 32.7 KB
    float* tk_l = lds;
    float* sv_l = lds + 7200;
    float* cv_l = lds + 8100;
    int blk = blockIdx.x, t = threadIdx.x;
    if (blk < 2000) {
        int b = blk / 80, cg = blk % 80;
        int c0 = cg * 8;
        for (int r = t; r < 7200; r += 256) tk_l[r] = task[c0 * 900 + r];
        for (int r = t; r < 900; r += 256) sv_l[r] = sksc[b * 900 + r];
        if (t < 72) cv_l[t] = cks[b * CKK + c0 * 9 + t];
        __syncthreads();
        const float* xb = sf + b * SF_B;
        float* ob = out + b * SF_B;
#pragma unroll
        for (int it = 0; it < 4; ++it) {
            int item = it * 256 + t;
            if (item >= 800) break;
            int cl = item / 100, p = item % 100;
            int i = p / 10, j = p % 10;
            const float* x = xb + (c0 + cl) * HWPIX;
            const float* tkp = tk_l + cl * 900 + p * 9;
            const float* svp = sv_l + p * 9;
            const float* cvp = cv_l + cl * 9;
            float acc = 0.f;
#pragma unroll
            for (int u = 0; u < 3; ++u) {
                int ii = i + u - 1;
                bool rowok = (ii >= 0) && (ii <= 9);
#pragma unroll
                for (int v = 0; v < 3; ++v) {
                    int jj = j + v - 1;
                    bool ok = rowok && (jj >= 0) && (jj <= 9);
                    float xv = ok ? x[ii * 10 + jj] : 0.f;
                    int uv = u * 3 + v;
                    acc += cvp[uv] * svp[uv] * tkp[uv] * xv;
                }
            }
            ob[(c0 + cl) * HWPIX + p] = acc;
        }
    } else {
        int qb = blk - 2000;
        int c = qb / 3, bg = qb % 3;
        for (int r = t; r < 900; r += 256) tk_l[r] = task[c * 900 + r];
        __syncthreads();
#pragma unroll
        for (int it = 0; it < 10; ++it) {
            int item = it * 256 + t;
            if (item >= 2500) break;
            int bl = item / 100, p = item % 100;
            int b = bg * 25 + bl;
            int i = p / 10, j = p % 10;
            const float* x = qf + b * SF_B + c * HWPIX;
            const float* tkp = tk_l + p * 9;
            float acc = 0.f;
#pragma unroll
            for (int u = 0; u < 3; ++u) {
                int ii = i + u - 1;
                bool rowok = (ii >= 0) && (ii <= 9);
#pragma unroll
                for (int v = 0; v < 3; ++v) {
                    int jj = j + v - 1;
                    bool ok = rowok && (jj >= 0) && (jj <= 9);
                    float xv = ok ? x[ii * 10 + jj] : 0.f;
                    acc += tkp[u * 3 + v] * xv;
                }
            }
            out[NBS * SF_B + b * SF_B + c * HWPIX + p] = acc;
        }
    }
}

extern "C" void kernel_launch(void* const* d_in, const int* in_sizes, int n_in,
                              void* d_out, int out_size, void* d_ws, size_t ws_size,
                              hipStream_t stream) {
    const float* sf  = (const float*)d_in[0];
    const float* qf  = (const float*)d_in[1];
    const float* Wc[4] = {(const float*)d_in[2], (const float*)d_in[4],
                          (const float*)d_in[6], (const float*)d_in[8]};
    const float* bc[4] = {(const float*)d_in[3], (const float*)d_in[5],
                          (const float*)d_in[7], (const float*)d_in[9]};
    const float* W1 = (const float*)d_in[10];
    const float* b1 = (const float*)d_in[11];
    const float* W2 = (const float*)d_in[12];
    const float* b2 = (const float*)d_in[13];
    const float* Ws = (const float*)d_in[14];
    const float* bs = (const float*)d_in[15];
    float* out = (float*)d_out;
    float* ws = (float*)d_ws;

    float* Pg0 = ws + OFF_PG0;
    float* Pga = ws + OFF_PGA;
    float* Pgb = ws + OFF_PGB;
    float* ATa = ws + OFF_ATA;
    float* ATb = ws + OFF_ATB;
    float* Ba  = ws + OFF_BA;
    float* Bb  = ws + OFF_BB;
    float* Hp  = ws + OFF_HP;
    float* SKT = ws + OFF_SKT;
    float* SKS = ws + OFF_SKS;
    float* SKSc= ws + OFF_SKSC;
    float* CKT = ws + OFF_CKT;
    float* CKS = ws + OFF_CKS;
    float* TSK = ws + OFF_TASK;

    pool_kernel<<<250, 64, 0, stream>>>(sf, Pg0);

    chain_step<<<4093, 256, 0, stream>>>(Pg0, Wc[0], bc[0], Pga, nullptr, Wc[3], bc[3], nullptr,
                                         ATa, Ba, 1, Ws, bs);
    chain_step<<<4093, 256, 0, stream>>>(Pga, Wc[1], bc[1], Pgb, ATa, Wc[2], bc[2], Ba,
                                         ATb, Bb, 0, Ws, bs);
    chain_step<<<4093, 256, 0, stream>>>(Pgb, Wc[2], bc[2], Pga, ATb, Wc[1], bc[1], Bb,
                                         ATa, Ba, 0, Ws, bs);
    chain_step<<<4093, 256, 0, stream>>>(Pga, Wc[3], bc[3], Pgb, ATa, Wc[0], bc[0], Ba,
                                         ATb, Bb, 0, Ws, bs);
    // pooled_t = Pgb, A4^T = ATb, beta4 = Bb

    postchain<<<276, 256, 0, stream>>>(sf, Pg0, Pgb, W1, Hp, ATb, Bb, Ws, bs, SKT, SKS);
    mlp_phase2<<<450, 320, 0, stream>>>(Hp, b1, W2, b2, CKT, CKS);
    task_assemble<<<2338, 256, 0, stream>>>(CKT, SKT, SKS, TSK, SKSc);
    involutions<<<3920, 256, 0, stream>>>(sf, qf, TSK, CKS, SKSc, out);
}

// Round 5
// 231.317 us; speedup vs baseline: 1.9644x; 1.0446x over previous
//
#include <hip/hip_runtime.h>

#define CCH   640
#define RDIM  128
#define HWPIX 100
#define NBS   25
#define NBQ   75
#define CKK   5760
#define SF_B  64000

// ---------------- Workspace layout (float offsets) ----------------
#define OFF_PG0   0        // [25][640] pooled, b-major
#define OFF_PGA   16000
#define OFF_PGB   32000
#define OFF_ATA   48000    // [640][9]
#define OFF_ATB   53760
#define OFF_BA    59520    // [16]
#define OFF_BB    59536
#define OFF_HP    59552    // [50][4][128] mlp1 partials
#define OFF_SKT   85152    // [2][25][900]  uv-major view layout: [b][uv*100+p]
#define OFF_SKS   130152   // [2][25][900]  same layout
#define OFF_SKSCT 175152   // [9][25][100]  combined instance sk, uv-major
#define OFF_CKT   197652   // [25][5760]
#define OFF_CKS   341652   // [25][5760]
#define OFF_TASKT 485652   // [9][640][100] task kernel transposed

// pooled(sf) -> [b][c] layout
__global__ void pool_kernel(const float* __restrict__ sf, float* __restrict__ Pg0) {
    int idx = blockIdx.x * 64 + threadIdx.x;
    if (idx >= NBS * CCH) return;
    int b = idx / CCH, c = idx % CCH;
    const float4* s4 = (const float4*)(sf + b * SF_B + c * HWPIX);
    float acc = 0.f;
#pragma unroll
    for (int q = 0; q < 25; ++q) {
        float4 v = s4[q];
        acc += (v.x + v.y) + (v.z + v.w);
    }
    Pg0[idx] = acc * 0.01f;
}

// One chain stage (same structure as R4).
__global__ void chain_step(const float* __restrict__ Pin, const float* __restrict__ Wp,
                           const float* __restrict__ bp, float* __restrict__ Pout,
                           const float* __restrict__ Ain, const float* __restrict__ Wa,
                           const float* __restrict__ ba, const float* __restrict__ Bin,
                           float* __restrict__ Aout, float* __restrict__ Bout,
                           int first, const float* __restrict__ Ws, const float* __restrict__ bs) {
    __shared__ float red[256];
    int blk = blockIdx.x, t = threadIdx.x;
    int lane = t & 63;
    if (blk < 4000) {
        int W = blk * 4 + (t >> 6);          // 0..15999
        int o = W / NBS, b = W % NBS;
        const float2* w2 = (const float2*)(Wp + o * CCH);
        const float2* p2 = (const float2*)(Pin + b * CCH);
        float acc = 0.f;
#pragma unroll
        for (int s = 0; s < 5; ++s) {
            float2 wv = w2[s * 64 + lane];
            float2 pv = p2[s * 64 + lane];
            acc += wv.x * pv.x + wv.y * pv.y;
        }
#pragma unroll
        for (int m = 32; m >= 1; m >>= 1) acc += __shfl_xor(acc, m);
        if (lane == 0) Pout[b * CCH + o] = acc + bp[o];
    } else if (blk < 4090) {
        int w = blk - 4000;                  // 0..89
        int k = w / 10, ctile = w % 10;
        int og = t >> 6, cl = lane;
        int c = ctile * 64 + cl;
        int o0 = og * 160;
        float acc = 0.f;
        if (first) {
            const float* ar = Ws + k * CCH;
#pragma unroll 8
            for (int o = o0; o < o0 + 160; ++o)
                acc += ar[o] * Wa[o * CCH + c];
        } else {
#pragma unroll 8
            for (int o = o0; o < o0 + 160; ++o)
                acc += Ain[o * 9 + k] * Wa[o * CCH + c];
        }
        red[t] = acc;
        __syncthreads();
        if (t < 64) {
            float s = red[t] + red[64 + t] + red[128 + t] + red[192 + t];
            Aout[(ctile * 64 + t) * 9 + k] = s;
        }
    } else {
        int WB = (blk - 4090) * 4 + (t >> 6);
        if (WB >= 9) return;
        int k = WB;
        float acc = 0.f;
        if (first) {
            const float* ar = Ws + k * CCH;
#pragma unroll
            for (int s = 0; s < 10; ++s) acc += ar[s * 64 + lane] * ba[s * 64 + lane];
        } else {
#pragma unroll
            for (int s = 0; s < 10; ++s) acc += Ain[(s * 64 + lane) * 9 + k] * ba[s * 64 + lane];
        }
#pragma unroll
        for (int m = 32; m >= 1; m >>= 1) acc += __shfl_xor(acc, m);
        if (lane == 0) Bout[k] = acc + (first ? bs[k] : Bin[k]);
    }
}

// mlp1 K-split partials + fused sk (both branches, c-split x2).
// sk value for compute-index (k,q) sits at flat f=k*100+q; stored in uv-major
// view layout: (p,uv) = (f/9, f%9) -> [b][uv*100+p].
__global__ void postchain(const float* __restrict__ sf, const float* __restrict__ Pg0,
                          const float* __restrict__ Pgf, const float* __restrict__ W1,
                          float* __restrict__ Hp, const float* __restrict__ A4T,
                          const float* __restrict__ betaF, const float* __restrict__ Ws,
                          const float* __restrict__ bs, float* __restrict__ SKT,
                          float* __restrict__ SKS) {
    int blk = blockIdx.x, t = threadIdx.x;
    if (blk < 100) {
        int pair = blk / 2;
        int s = (blk % 2) * 2 + (t >> 7);
        int r = t & 127;
        int branch = pair / NBS, b = pair % NBS;
        const float* prow = (branch ? Pg0 : Pgf) + b * CCH;
        int c0 = s * 160;
        float acc = 0.f;
#pragma unroll 8
        for (int c = 0; c < 160; ++c)
            acc += prow[c0 + c] * W1[(c0 + c) * RDIM + r];
        Hp[(pair * 4 + s) * RDIM + r] = acc;
    } else {
        int sidx = (blk - 100) * 256 + t;
        if (sidx >= 45000) return;
        int s = sidx / 22500;
        int rem = sidx % 22500;
        int b = rem / 900;
        int r2 = rem % 900;          // flat f = k*100 + q
        int k = r2 / HWPIX, q = r2 % HWPIX;
        const float* x = sf + b * SF_B + q;
        const float* wsr = Ws + k * CCH;
        int c0 = s * 320;
        float acc0 = 0.f, acc1 = 0.f;
#pragma unroll 8
        for (int c = 0; c < 320; ++c) {
            float xc = x[(c0 + c) * HWPIX];
            acc0 += A4T[(c0 + c) * 9 + k] * xc;
            acc1 += wsr[c0 + c] * xc;
        }
        if (s == 0) { acc0 += betaF[k]; acc1 += bs[k]; }
        int p = r2 / 9, uv = r2 % 9;           // view coords of flat offset r2
        int dst = s * 22500 + b * 900 + uv * 100 + p;
        SKT[dst] = acc0;
        SKS[dst] = acc1;
    }
}

// ck for both branches per block: 225 blocks (b x 9 chunks of 640 j), 320 threads
__global__ void mlp_phase2(const float* __restrict__ Hp, const float* __restrict__ b1,
                           const float* __restrict__ W2, const float* __restrict__ b2,
                           float* __restrict__ ckt, float* __restrict__ cks) {
    __shared__ float hs0[RDIM], hs1[RDIM];
    int b = blockIdx.x / 9, chunk = blockIdx.x % 9;
    int t = threadIdx.x;
    if (t < RDIM) {
        const float* hp = Hp + b * 4 * RDIM;
        hs0[t] = fmaxf(b1[t] + hp[t] + hp[RDIM + t] + hp[2 * RDIM + t] + hp[3 * RDIM + t], 0.f);
    } else if (t < 2 * RDIM) {
        int r = t - RDIM;
        const float* hp = Hp + (NBS + b) * 4 * RDIM;
        hs1[r] = fmaxf(b1[r] + hp[r] + hp[RDIM + r] + hp[2 * RDIM + r] + hp[3 * RDIM + r], 0.f);
    }
    __syncthreads();
    int jbase = chunk * 640;
    float a00 = b2[jbase + t], a01 = b2[jbase + t + 320];
    float a10 = a00, a11 = a01;
#pragma unroll 4
    for (int r = 0; r < RDIM; ++r) {
        const float* wrow = W2 + r * CKK + jbase;
        float w0 = wrow[t], w1 = wrow[t + 320];
        float h0 = hs0[r], h1 = hs1[r];
        a00 += h0 * w0; a01 += h0 * w1;
        a10 += h1 * w0; a11 += h1 * w1;
    }
    float* c0 = ckt + b * CKK + jbase;
    float* c1 = cks + b * CKK + jbase;
    c0[t] = a00; c0[t + 320] = a01;
    c1[t] = a10; c1[t + 320] = a11;
}

// taskT[uv*64000 + c*100 + p] = (1/25) sum_b ckt[b][c*9+uv] * skt[b][uv*100+p]
// blocks [2250,2338): sksT[uv*2500 + b*100 + p] = sum of SKS parts
__global__ void task_assemble(const float* __restrict__ ckt, const float* __restrict__ SKT,
                              const float* __restrict__ SKS, float* __restrict__ taskT,
                              float* __restrict__ sksT) {
    int blk = blockIdx.x, t = threadIdx.x;
    if (blk < 2250) {
        int idx = blk * 256 + t;          // uv*64000 + c*100 + p
        int uv = idx / 64000;
        int rem = idx % 64000;
        int c = rem / 100, p = rem % 100;
        float acc = 0.f;
#pragma unroll
        for (int b = 0; b < NBS; ++b)
            acc += ckt[b * CKK + c * 9 + uv] *
                   (SKT[b * 900 + uv * 100 + p] + SKT[22500 + b * 900 + uv * 100 + p]);
        taskT[idx] = acc * 0.04f;
    } else {
        int cidx = (blk - 2250) * 256 + t;
        if (cidx >= 22500) return;
        int uv = cidx / 2500;
        int r = cidx % 2500;              // b*100+p
        int src = (r / 100) * 900 + uv * 100 + (r % 100);
        sksT[cidx] = SKS[src] + SKS[22500 + src];
    }
}

// Merged involutions, thread per output element, NO LDS.
// idx < 1.6M: support; else query. All taps coalesced via transposed layouts.
__global__ __launch_bounds__(256) void involutions(
        const float* __restrict__ sf, const float* __restrict__ qf,
        const float* __restrict__ taskT, const float* __restrict__ cks,
        const float* __restrict__ sksT, float* __restrict__ out) {
    int idx = blockIdx.x * 256 + threadIdx.x;     // max 6.4M
    bool support = idx < NBS * SF_B;
    int b, c, p;
    const float* x;
    if (support) {
        b = idx / SF_B; int rem = idx % SF_B; c = rem / 100; p = rem % 100;
        x = sf + b * SF_B + c * 100;
    } else {
        int qidx = idx - NBS * SF_B;
        b = qidx / SF_B; int rem = qidx % SF_B; c = rem / 100; p = rem % 100;
        x = qf + b * SF_B + c * 100;
    }
    int i = p / 10, j = p % 10;
    float acc = 0.f;
#pragma unroll
    for (int u = 0; u < 3; ++u) {
        int ii = i + u - 1;
        float mrow = ((unsigned)ii < 10u) ? 1.f : 0.f;
        int ci = min(max(ii, 0), 9);
#pragma unroll
        for (int v = 0; v < 3; ++v) {
            int jj = j + v - 1;
            float m = ((unsigned)jj < 10u) ? mrow : 0.f;
            int cj = min(max(jj, 0), 9);
            float xv = x[ci * 10 + cj] * m;     // clamped addr, masked value
            int uv = u * 3 + v;
            float w = taskT[uv * 64000 + c * 100 + p];
            if (support)
                w *= cks[b * CKK + c * 9 + uv] * sksT[uv * 2500 + b * 100 + p];
            acc += w * xv;
        }
    }
    out[idx] = acc;
}

extern "C" void kernel_launch(void* const* d_in, const int* in_sizes, int n_in,
                              void* d_out, int out_size, void* d_ws, size_t ws_size,
                              hipStream_t stream) {
    const float* sf  = (const float*)d_in[0];
    const float* qf  = (const float*)d_in[1];
    const float* Wc[4] = {(const float*)d_in[2], (const float*)d_in[4],
                          (const float*)d_in[6], (const float*)d_in[8]};
    const float* bc[4] = {(const float*)d_in[3], (const float*)d_in[5],
                          (const float*)d_in[7], (const float*)d_in[9]};
    const float* W1 = (const float*)d_in[10];
    const float* b1 = (const float*)d_in[11];
    const float* W2 = (const float*)d_in[12];
    const float* b2 = (const float*)d_in[13];
    const float* Ws = (const float*)d_in[14];
    const float* bs = (const float*)d_in[15];
    float* out = (float*)d_out;
    float* ws = (float*)d_ws;

    float* Pg0 = ws + OFF_PG0;
    float* Pga = ws + OFF_PGA;
    float* Pgb = ws + OFF_PGB;
    float* ATa = ws + OFF_ATA;
    float* ATb = ws + OFF_ATB;
    float* Ba  = ws + OFF_BA;
    float* Bb  = ws + OFF_BB;
    float* Hp  = ws + OFF_HP;
    float* SKT = ws + OFF_SKT;
    float* SKS = ws + OFF_SKS;
    float* SKsT= ws + OFF_SKSCT;
    float* CKT = ws + OFF_CKT;
    float* CKS = ws + OFF_CKS;
    float* TKT = ws + OFF_TASKT;

    pool_kernel<<<250, 64, 0, stream>>>(sf, Pg0);

    chain_step<<<4093, 256, 0, stream>>>(Pg0, Wc[0], bc[0], Pga, nullptr, Wc[3], bc[3], nullptr,
                                         ATa, Ba, 1, Ws, bs);
    chain_step<<<4093, 256, 0, stream>>>(Pga, Wc[1], bc[1], Pgb, ATa, Wc[2], bc[2], Ba,
                                         ATb, Bb, 0, Ws, bs);
    chain_step<<<4093, 256, 0, stream>>>(Pgb, Wc[2], bc[2], Pga, ATb, Wc[1], bc[1], Bb,
                                         ATa, Ba, 0, Ws, bs);
    chain_step<<<4093, 256, 0, stream>>>(Pga, Wc[3], bc[3], Pgb, ATa, Wc[0], bc[0], Ba,
                                         ATb, Bb, 0, Ws, bs);
    // pooled_t = Pgb, A4^T = ATb, beta4 = Bb

    postchain<<<276, 256, 0, stream>>>(sf, Pg0, Pgb, W1, Hp, ATb, Bb, Ws, bs, SKT, SKS);
    mlp_phase2<<<225, 320, 0, stream>>>(Hp, b1, W2, b2, CKT, CKS);
    task_assemble<<<2338, 256, 0, stream>>>(CKT, SKT, SKS, TKT, SKsT);
    involutions<<<25000, 256, 0, stream>>>(sf, qf, TKT, CKS, SKsT, out);
}